// Round 6
// baseline (4378.672 us; speedup 1.0000x reference)
//
#include <hip/hip_runtime.h>
#include <hip/hip_bf16.h>

// RNN scan on MI355X — round 6: 4-CU WG-local, 4 waves x 128 cols.
// k1: xw[t][b][n] = bf16(x[b,t,:] @ W_x + b_x + b_h); 4 t per WG (W_x staged once).
// k2: grid=4, WG owns 16 batch rows x all 512 cols. 4 waves (1/SIMD, 512-reg
//     budget): W_h k<384 in register A-frags wfA[8][12] (384 regs, all indices
//     compile-time); k in [384,512) in LDS (128 KB, frag-linear). hT double-
//     buffered (2 x 16 KB) -> ONE barrier/step. FC epilogue fused, single
//     writer per b (no memsets). No inter-WG traffic.

#define T_STEPS 1024
#define HID     512

typedef __attribute__((ext_vector_type(8))) short  short8;   // 8 bf16 (MFMA A/B frag)
typedef __attribute__((ext_vector_type(4))) short  short4_t; // 4 bf16 (8 B)
typedef __attribute__((ext_vector_type(4))) float  f32x4;    // MFMA C/D frag

typedef unsigned short ushort_t;
typedef unsigned int   uint_t;

__device__ __forceinline__ ushort_t f2bf(float f) {
    union { float f; uint_t u; } c; c.f = f;
    uint_t u = c.u;
    return (ushort_t)((u + 0x7fffu + ((u >> 16) & 1u)) >> 16);   // RNE
}
__device__ __forceinline__ float bf2f(ushort_t h) {
    union { uint_t u; float f; } c; c.u = ((uint_t)h) << 16;
    return c.f;
}
// tanh(x) = 1 - 2/(e^{2x}+1); exp2-based, saturates correctly at +/-1.
__device__ __forceinline__ float tanh_fast(float x) {
    float t = __builtin_amdgcn_exp2f(x * 2.88539008f);   // e^{2x}
    return 1.0f - 2.0f * __builtin_amdgcn_rcpf(t + 1.0f);
}

// ---------------------------------------------------------------------------
// k1: xw[t][b][n], transposed MFMA: A = W_x^T (m=n), B = x^T (n=b).
// Grid (8, 256): n0 = bx*64, t0 = by*4 (4 timesteps share one W_x staging).
// ---------------------------------------------------------------------------
__global__ __launch_bounds__(256) void k1_xproj(
    const float* __restrict__ x, const float* __restrict__ Wx,
    const float* __restrict__ bx, const float* __restrict__ bh,
    ushort_t* __restrict__ xw)
{
    __shared__ __align__(16) ushort_t Wl[64 * 40];        // [n][k]
    __shared__ __align__(16) ushort_t Xl[4][64 * 40];     // [tt][b][k]

    const int t0   = blockIdx.y * 4;
    const int n0   = blockIdx.x * 64;
    const int tid  = threadIdx.x;
    const int wave = tid >> 6;
    const int lane = tid & 63;
    const int lm   = lane & 15;
    const int quad = lane >> 4;

    f32x4 acc[4][4];
    #pragma unroll
    for (int tt = 0; tt < 4; ++tt)
        #pragma unroll
        for (int i = 0; i < 4; ++i) acc[tt][i] = (f32x4){0.f, 0.f, 0.f, 0.f};

    float biasv[4];
    #pragma unroll
    for (int r = 0; r < 4; ++r) {
        int n = n0 + wave * 16 + quad * 4 + r;
        biasv[r] = bx[n] + bh[n];
    }

    const int ar = tid >> 2, ac = (tid & 3) * 8;   // X staging: b row, 8 k's
    const int bk = tid >> 3, bc = (tid & 7) * 8;   // W staging: k, 8 n's

    for (int kb = 0; kb < 16; ++kb) {
        { // stage W_x swizzled: Wl[n][k] (once per kb, shared by 4 t's)
            const float* bp = Wx + (size_t)(kb * 32 + bk) * HID + n0 + bc;
            #pragma unroll
            for (int i = 0; i < 8; ++i) Wl[(bc + i) * 40 + bk] = f2bf(bp[i]);
        }
        #pragma unroll
        for (int tt = 0; tt < 4; ++tt) { // stage x rows for 4 t's
            const float* ap = x + ((size_t)ar * T_STEPS + t0 + tt) * HID + kb * 32 + ac;
            short8 pack;
            #pragma unroll
            for (int i = 0; i < 8; ++i) pack[i] = (short)f2bf(ap[i]);
            *(short8*)&Xl[tt][ar * 40 + ac] = pack;
        }
        __syncthreads();
        short8 afr = *(const short8*)&Wl[(wave * 16 + lm) * 40 + quad * 8];
        #pragma unroll
        for (int tt = 0; tt < 4; ++tt)
            #pragma unroll
            for (int bt = 0; bt < 4; ++bt) {
                short8 bfr = *(const short8*)&Xl[tt][(bt * 16 + lm) * 40 + quad * 8];
                acc[tt][bt] = __builtin_amdgcn_mfma_f32_16x16x32_bf16(afr, bfr, acc[tt][bt], 0, 0, 0);
            }
        __syncthreads();
    }

    // D layout: col = b = lm (+bt*16), row = n_local = quad*4+r (+wave*16)
    #pragma unroll
    for (int tt = 0; tt < 4; ++tt)
        #pragma unroll
        for (int bt = 0; bt < 4; ++bt) {
            short4_t pk;
            #pragma unroll
            for (int r = 0; r < 4; ++r) pk[r] = (short)f2bf(acc[tt][bt][r] + biasv[r]);
            *(short4_t*)&xw[((size_t)(t0 + tt) * 64 + bt * 16 + lm) * HID
                            + n0 + wave * 16 + quad * 4] = pk;
        }
}

// ---------------------------------------------------------------------------
// k2: grid=4 x 256 threads (4 waves, 1/SIMD). Wave owns 128 cols.
// LDS (ushort):
//   hT[2][8192]  : h B-frags, frag-linear, double-buffered (2 x 16 KB)
//   Wl[65536]    : W_h A-frags for k in [384,512) (128 KB)
// hT element (b,k): (kt*64 + ((k>>3)&3)*16 + b)*8 + (k&7), kt = k>>5.
// ---------------------------------------------------------------------------
__global__ __launch_bounds__(256, 1) void k2_scan(
    const ushort_t* __restrict__ xw, const float* __restrict__ Wh,
    const float* __restrict__ Wfc, const float* __restrict__ bfc,
    float* __restrict__ out)
{
    __shared__ __align__(16) ushort_t hT[2][8192];
    __shared__ __align__(16) ushort_t Wl[65536];

    const int tid  = threadIdx.x;
    const int wave = tid >> 6;
    const int lane = tid & 63;
    const int lm   = lane & 15;
    const int quad = lane >> 4;
    const int rowbase = blockIdx.x * 16;   // batch rows
    const int colb    = wave * 128;        // wave's first output column

    // h_0 = 0 (only buffer 0; buffer 1 is fully written at t=0)
    for (int i = tid; i < 8192; i += 256) hT[0][i] = 0;

    // Wl init: frag c: ktp = c>>11, mtg = (c>>6)&31, l = c&63 holds A-frag for
    // m = n = mtg*16 + (l&15), k = (12+ktp)*32 + (l>>4)*8 + j
    for (int i = 0; i < 32; ++i) {
        int c   = i * 256 + tid;
        int l   = c & 63;
        int mtg = (c >> 6) & 31;
        int ktp = c >> 11;
        int n   = mtg * 16 + (l & 15);
        int kb  = (12 + ktp) * 32 + (l >> 4) * 8;
        short8 w;
        #pragma unroll
        for (int j = 0; j < 8; ++j) w[j] = (short)f2bf(Wh[(size_t)(kb + j) * HID + n]);
        *(short8*)&Wl[(size_t)c * 8] = w;
    }

    // wfA[mt][kt]: A[m = colb+mt*16+lm][k = kt*32+quad*8+j], k in [0,384).
    // ALL register indices compile-time.
    short8 wfA[8][12];
    #pragma unroll
    for (int mt = 0; mt < 8; ++mt) {
        const int n = colb + mt * 16 + lm;
        #pragma unroll
        for (int kt = 0; kt < 12; ++kt) {
            short8 w;
            #pragma unroll
            for (int j = 0; j < 8; ++j)
                w[j] = (short)f2bf(Wh[(size_t)(kt * 32 + quad * 8 + j) * HID + n]);
            wfA[mt][kt] = w;
        }
    }
    __syncthreads();

    for (int t = 0; t < T_STEPS; ++t) {
        // xw loads: one b64 per mt (consumed only pre-tanh -> latency hidden)
        short4_t xv[8];
        #pragma unroll
        for (int mt = 0; mt < 8; ++mt)
            xv[mt] = *(const short4_t*)&xw[((size_t)t * 64 + rowbase + lm) * HID
                                           + colb + mt * 16 + quad * 4];

        f32x4 acc[8];
        #pragma unroll
        for (int mt = 0; mt < 8; ++mt) acc[mt] = (f32x4){0.f, 0.f, 0.f, 0.f};

        const ushort_t* cur = hT[t & 1];
        // k in [0,384): A from registers, B (h) from LDS
        #pragma unroll
        for (int kt = 0; kt < 12; ++kt) {
            short8 b = *(const short8*)&cur[(kt * 64 + lane) * 8];
            #pragma unroll
            for (int mt = 0; mt < 8; ++mt)
                acc[mt] = __builtin_amdgcn_mfma_f32_16x16x32_bf16(wfA[mt][kt], b, acc[mt], 0, 0, 0);
        }
        // k in [384,512): A from LDS
        #pragma unroll
        for (int ktp = 0; ktp < 4; ++ktp) {
            short8 b = *(const short8*)&cur[((12 + ktp) * 64 + lane) * 8];
            #pragma unroll
            for (int mt = 0; mt < 8; ++mt) {
                short8 a = *(const short8*)&Wl[(size_t)((ktp * 32 + wave * 8 + mt) * 64 + lane) * 8];
                acc[mt] = __builtin_amdgcn_mfma_f32_16x16x32_bf16(a, b, acc[mt], 0, 0, 0);
            }
        }

        // h_{t+1} = tanh(acc + xw) -> other hT buffer (packed b64 stores)
        ushort_t* nxt = hT[(t + 1) & 1];
        #pragma unroll
        for (int mt = 0; mt < 8; ++mt) {
            float v0 = tanh_fast(acc[mt][0] + bf2f((ushort_t)xv[mt][0]));
            float v1 = tanh_fast(acc[mt][1] + bf2f((ushort_t)xv[mt][1]));
            float v2 = tanh_fast(acc[mt][2] + bf2f((ushort_t)xv[mt][2]));
            float v3 = tanh_fast(acc[mt][3] + bf2f((ushort_t)xv[mt][3]));
            union { short4_t v; __hip_bfloat162 h[2]; } cv;
            cv.h[0] = __float22bfloat162_rn(float2{v0, v1});
            cv.h[1] = __float22bfloat162_rn(float2{v2, v3});
            // n = colb + mt*16 + quad*4 ; kt = n>>5 = wave*4 + (mt>>1)
            const int off = ((wave * 4 + (mt >> 1)) * 64
                             + ((mt & 1) * 2 + (quad >> 1)) * 16 + lm) * 8
                            + (quad & 1) * 4;
            *(short4_t*)&nxt[off] = cv.v;
        }

        __syncthreads();   // ONE barrier: h_{t+1} complete before next step reads
    }

    // fused FC epilogue: out[rowbase+b] = h_T[b,:] . W_fc + b_fc
    // wave handles b = wave*4 + bb; lane covers k = lane*8 .. +8 (one b128)
    const ushort_t* fin = hT[T_STEPS & 1];
    #pragma unroll
    for (int bb = 0; bb < 4; ++bb) {
        const int b = wave * 4 + bb;
        short8 hv = *(const short8*)&fin[(((lane >> 2) * 64 + (lane & 3) * 16 + b) * 8)];
        float s = 0.f;
        #pragma unroll
        for (int j = 0; j < 8; ++j) s += bf2f((ushort_t)hv[j]) * Wfc[lane * 8 + j];
        #pragma unroll
        for (int off = 32; off; off >>= 1) s += __shfl_down(s, off, 64);
        if (lane == 0) out[rowbase + b] = s + bfc[0];
    }
}

// ---------------------------------------------------------------------------
extern "C" void kernel_launch(void* const* d_in, const int* in_sizes, int n_in,
                              void* d_out, int out_size, void* d_ws, size_t ws_size,
                              hipStream_t stream)
{
    const float* x   = (const float*)d_in[0];
    const float* Wx  = (const float*)d_in[1];
    const float* bx  = (const float*)d_in[2];
    const float* Wh  = (const float*)d_in[3];
    const float* bh  = (const float*)d_in[4];
    const float* Wfc = (const float*)d_in[5];
    const float* bfc = (const float*)d_in[6];
    float* out = (float*)d_out;

    // ws: xw bf16 [1024 t][64 b][512 n] = 64 MiB
    ushort_t* xw = (ushort_t*)d_ws;

    k1_xproj<<<dim3(8, 256), 256, 0, stream>>>(x, Wx, bx, bh, xw);
    k2_scan <<<dim3(4),      256, 0, stream>>>(xw, Wh, Wfc, bfc, out);
}

// Round 7
// 2772.282 us; speedup vs baseline: 1.5794x; 1.5794x over previous
//
#include <hip/hip_runtime.h>
#include <hip/hip_bf16.h>

// RNN scan on MI355X — round 7: r4's 8-wave/2-per-SIMD structure +
// single barrier (double-buffered hT) + wfA[4][13] (Wl down to 3 k-slices).
// k1: xw[t][b][n] = bf16(x[b,t,:] @ W_x + b_x + b_h); 4 t per WG.
// k2: grid=4, WG owns 16 batch rows x all 512 cols; 8 waves x 64 cols.
//     W_h k<416 in register A-frags wfA[4][13] (208 regs, compile-time
//     indices); k in [416,512) in LDS Wl (96 KB). hT double-buffered
//     (2 x 16 KB) -> ONE barrier/step. FC fused. No inter-WG traffic.

#define T_STEPS 1024
#define HID     512

typedef __attribute__((ext_vector_type(8))) short  short8;   // 8 bf16 (MFMA A/B frag)
typedef __attribute__((ext_vector_type(4))) short  short4_t; // 4 bf16 (8 B)
typedef __attribute__((ext_vector_type(4))) float  f32x4;    // MFMA C/D frag

typedef unsigned short ushort_t;
typedef unsigned int   uint_t;

__device__ __forceinline__ ushort_t f2bf(float f) {
    union { float f; uint_t u; } c; c.f = f;
    uint_t u = c.u;
    return (ushort_t)((u + 0x7fffu + ((u >> 16) & 1u)) >> 16);   // RNE
}
__device__ __forceinline__ float bf2f(ushort_t h) {
    union { uint_t u; float f; } c; c.u = ((uint_t)h) << 16;
    return c.f;
}
// tanh(x) = 1 - 2/(e^{2x}+1); exp2-based, saturates correctly at +/-1.
__device__ __forceinline__ float tanh_fast(float x) {
    float t = __builtin_amdgcn_exp2f(x * 2.88539008f);   // e^{2x}
    return 1.0f - 2.0f * __builtin_amdgcn_rcpf(t + 1.0f);
}

// ---------------------------------------------------------------------------
// k1: xw[t][b][n], transposed MFMA: A = W_x^T (m=n), B = x^T (n=b).
// Grid (8, 256): n0 = bx*64, t0 = by*4 (4 timesteps share one W_x staging).
// ---------------------------------------------------------------------------
__global__ __launch_bounds__(256) void k1_xproj(
    const float* __restrict__ x, const float* __restrict__ Wx,
    const float* __restrict__ bx, const float* __restrict__ bh,
    ushort_t* __restrict__ xw)
{
    __shared__ __align__(16) ushort_t Wl[64 * 40];        // [n][k]
    __shared__ __align__(16) ushort_t Xl[4][64 * 40];     // [tt][b][k]

    const int t0   = blockIdx.y * 4;
    const int n0   = blockIdx.x * 64;
    const int tid  = threadIdx.x;
    const int wave = tid >> 6;
    const int lane = tid & 63;
    const int lm   = lane & 15;
    const int quad = lane >> 4;

    f32x4 acc[4][4];
    #pragma unroll
    for (int tt = 0; tt < 4; ++tt)
        #pragma unroll
        for (int i = 0; i < 4; ++i) acc[tt][i] = (f32x4){0.f, 0.f, 0.f, 0.f};

    float biasv[4];
    #pragma unroll
    for (int r = 0; r < 4; ++r) {
        int n = n0 + wave * 16 + quad * 4 + r;
        biasv[r] = bx[n] + bh[n];
    }

    const int ar = tid >> 2, ac = (tid & 3) * 8;   // X staging: b row, 8 k's
    const int bk = tid >> 3, bc = (tid & 7) * 8;   // W staging: k, 8 n's

    for (int kb = 0; kb < 16; ++kb) {
        { // stage W_x swizzled: Wl[n][k] (once per kb, shared by 4 t's)
            const float* bp = Wx + (size_t)(kb * 32 + bk) * HID + n0 + bc;
            #pragma unroll
            for (int i = 0; i < 8; ++i) Wl[(bc + i) * 40 + bk] = f2bf(bp[i]);
        }
        #pragma unroll
        for (int tt = 0; tt < 4; ++tt) { // stage x rows for 4 t's
            const float* ap = x + ((size_t)ar * T_STEPS + t0 + tt) * HID + kb * 32 + ac;
            short8 pack;
            #pragma unroll
            for (int i = 0; i < 8; ++i) pack[i] = (short)f2bf(ap[i]);
            *(short8*)&Xl[tt][ar * 40 + ac] = pack;
        }
        __syncthreads();
        short8 afr = *(const short8*)&Wl[(wave * 16 + lm) * 40 + quad * 8];
        #pragma unroll
        for (int tt = 0; tt < 4; ++tt)
            #pragma unroll
            for (int bt = 0; bt < 4; ++bt) {
                short8 bfr = *(const short8*)&Xl[tt][(bt * 16 + lm) * 40 + quad * 8];
                acc[tt][bt] = __builtin_amdgcn_mfma_f32_16x16x32_bf16(afr, bfr, acc[tt][bt], 0, 0, 0);
            }
        __syncthreads();
    }

    // D layout: col = b = lm (+bt*16), row = n_local = quad*4+r (+wave*16)
    #pragma unroll
    for (int tt = 0; tt < 4; ++tt)
        #pragma unroll
        for (int bt = 0; bt < 4; ++bt) {
            short4_t pk;
            #pragma unroll
            for (int r = 0; r < 4; ++r) pk[r] = (short)f2bf(acc[tt][bt][r] + biasv[r]);
            *(short4_t*)&xw[((size_t)(t0 + tt) * 64 + bt * 16 + lm) * HID
                            + n0 + wave * 16 + quad * 4] = pk;
        }
}

// ---------------------------------------------------------------------------
// k2: grid=4 x 512 threads (8 waves, 2/SIMD). Wave owns 64 cols.
// LDS (ushort):
//   hT[2][8192] : h B-frags, frag-linear, double-buffered (2 x 16 KB)
//   Wl[49152]   : W_h A-frags for k in [416,512) (96 KB)
// hT element (b,k): (kt*64 + ((k>>3)&3)*16 + b)*8 + (k&7), kt = k>>5.
// Wl frag c = (ktp*32 + mtg)*64 + l: m = n = mtg*16+(l&15),
//   k = (13+ktp)*32 + (l>>4)*8 + j.
// ---------------------------------------------------------------------------
__global__ __launch_bounds__(512, 2) void k2_scan(
    const ushort_t* __restrict__ xw, const float* __restrict__ Wh,
    const float* __restrict__ Wfc, const float* __restrict__ bfc,
    float* __restrict__ out)
{
    __shared__ __align__(16) ushort_t hT[2][8192];
    __shared__ __align__(16) ushort_t Wl[49152];

    const int tid  = threadIdx.x;
    const int wave = tid >> 6;
    const int lane = tid & 63;
    const int lm   = lane & 15;
    const int quad = lane >> 4;
    const int rowbase = blockIdx.x * 16;   // batch rows
    const int colb    = wave * 64;         // wave's first output column

    // h_0 = 0 (buffer 0 only; buffer 1 fully written at t=0)
    for (int i = tid; i < 8192; i += 512) hT[0][i] = 0;

    // Wl init: 3*32*64 = 6144 frags
    for (int i = 0; i < 12; ++i) {
        int c   = i * 512 + tid;
        int l   = c & 63;
        int mtg = (c >> 6) & 31;
        int ktp = c >> 11;
        int n   = mtg * 16 + (l & 15);
        int kb  = (13 + ktp) * 32 + (l >> 4) * 8;
        short8 w;
        #pragma unroll
        for (int j = 0; j < 8; ++j) w[j] = (short)f2bf(Wh[(size_t)(kb + j) * HID + n]);
        *(short8*)&Wl[(size_t)c * 8] = w;
    }

    // wfA[mt][kt]: A[m = colb+mt*16+lm][k = kt*32+quad*8+j], k in [0,416).
    // ALL register indices compile-time.
    short8 wfA[4][13];
    #pragma unroll
    for (int mt = 0; mt < 4; ++mt) {
        const int n = colb + mt * 16 + lm;
        #pragma unroll
        for (int kt = 0; kt < 13; ++kt) {
            short8 w;
            #pragma unroll
            for (int j = 0; j < 8; ++j)
                w[j] = (short)f2bf(Wh[(size_t)(kt * 32 + quad * 8 + j) * HID + n]);
            wfA[mt][kt] = w;
        }
    }
    __syncthreads();

    for (int t = 0; t < T_STEPS; ++t) {
        // xw loads: one b64 per mt (consumed only pre-tanh -> latency hidden)
        short4_t xv[4];
        #pragma unroll
        for (int mt = 0; mt < 4; ++mt)
            xv[mt] = *(const short4_t*)&xw[((size_t)t * 64 + rowbase + lm) * HID
                                           + colb + mt * 16 + quad * 4];

        f32x4 acc[4];
        #pragma unroll
        for (int mt = 0; mt < 4; ++mt) acc[mt] = (f32x4){0.f, 0.f, 0.f, 0.f};

        const ushort_t* cur = hT[t & 1];
        // k in [0,416): A from registers, B (h) from LDS
        #pragma unroll
        for (int kt = 0; kt < 13; ++kt) {
            short8 b = *(const short8*)&cur[(kt * 64 + lane) * 8];
            #pragma unroll
            for (int mt = 0; mt < 4; ++mt)
                acc[mt] = __builtin_amdgcn_mfma_f32_16x16x32_bf16(wfA[mt][kt], b, acc[mt], 0, 0, 0);
        }
        // k in [416,512): A from LDS
        #pragma unroll
        for (int ktp = 0; ktp < 3; ++ktp) {
            short8 b = *(const short8*)&cur[((13 + ktp) * 64 + lane) * 8];
            #pragma unroll
            for (int mt = 0; mt < 4; ++mt) {
                short8 a = *(const short8*)&Wl[(size_t)((ktp * 32 + wave * 4 + mt) * 64 + lane) * 8];
                acc[mt] = __builtin_amdgcn_mfma_f32_16x16x32_bf16(a, b, acc[mt], 0, 0, 0);
            }
        }

        // h_{t+1} = tanh(acc + xw) -> other hT buffer (packed b64 stores)
        ushort_t* nxt = hT[(t + 1) & 1];
        #pragma unroll
        for (int mt = 0; mt < 4; ++mt) {
            float v0 = tanh_fast(acc[mt][0] + bf2f((ushort_t)xv[mt][0]));
            float v1 = tanh_fast(acc[mt][1] + bf2f((ushort_t)xv[mt][1]));
            float v2 = tanh_fast(acc[mt][2] + bf2f((ushort_t)xv[mt][2]));
            float v3 = tanh_fast(acc[mt][3] + bf2f((ushort_t)xv[mt][3]));
            union { short4_t v; __hip_bfloat162 h[2]; } cv;
            cv.h[0] = __float22bfloat162_rn(float2{v0, v1});
            cv.h[1] = __float22bfloat162_rn(float2{v2, v3});
            const int n = colb + mt * 16 + quad * 4;
            *(short4_t*)&nxt[((n >> 5) * 64 + ((n >> 3) & 3) * 16 + lm) * 8 + (n & 7)] = cv.v;
        }

        __syncthreads();   // ONE barrier: h_{t+1} complete before next step reads
    }

    // fused FC epilogue: out[rowbase+b] = h_T[b,:] . W_fc + b_fc
    // wave handles b = wave*2 + bb; lane covers k = lane*8 .. +8 (one b128)
    const ushort_t* fin = hT[T_STEPS & 1];
    #pragma unroll
    for (int bb = 0; bb < 2; ++bb) {
        const int b = wave * 2 + bb;
        short8 hv = *(const short8*)&fin[(((lane >> 2) * 64 + (lane & 3) * 16 + b) * 8)];
        float s = 0.f;
        #pragma unroll
        for (int j = 0; j < 8; ++j) s += bf2f((ushort_t)hv[j]) * Wfc[lane * 8 + j];
        #pragma unroll
        for (int off = 32; off; off >>= 1) s += __shfl_down(s, off, 64);
        if (lane == 0) out[rowbase + b] = s + bfc[0];
    }
}

// ---------------------------------------------------------------------------
extern "C" void kernel_launch(void* const* d_in, const int* in_sizes, int n_in,
                              void* d_out, int out_size, void* d_ws, size_t ws_size,
                              hipStream_t stream)
{
    const float* x   = (const float*)d_in[0];
    const float* Wx  = (const float*)d_in[1];
    const float* bx  = (const float*)d_in[2];
    const float* Wh  = (const float*)d_in[3];
    const float* bh  = (const float*)d_in[4];
    const float* Wfc = (const float*)d_in[5];
    const float* bfc = (const float*)d_in[6];
    float* out = (float*)d_out;

    // ws: xw bf16 [1024 t][64 b][512 n] = 64 MiB
    ushort_t* xw = (ushort_t*)d_ws;

    k1_xproj<<<dim3(8, 256), 256, 0, stream>>>(x, Wx, bx, bh, xw);
    k2_scan <<<dim3(4),      512, 0, stream>>>(xw, Wh, Wfc, bfc, out);
}

// Round 8
// 2264.275 us; speedup vs baseline: 1.9338x; 1.2244x over previous
//
#include <hip/hip_runtime.h>
#include <hip/hip_bf16.h>

// RNN scan on MI355X — round 8.
// k1: retiled — grid (2 n-halves, 256 t-quads), 512 thr; x re-read 8x -> 2x.
// k2: r4's 12/4 register/LDS split (register slack!) + single barrier via
//     double-buffered hT + strength-reduced xw pointer. 8 waves, 2/SIMD.

#define T_STEPS 1024
#define HID     512

typedef __attribute__((ext_vector_type(8))) short  short8;   // 8 bf16 (MFMA A/B frag)
typedef __attribute__((ext_vector_type(4))) short  short4_t; // 4 bf16 (8 B)
typedef __attribute__((ext_vector_type(4))) float  f32x4;    // MFMA C/D frag
typedef __attribute__((ext_vector_type(4))) float  float4_t;

typedef unsigned short ushort_t;
typedef unsigned int   uint_t;

__device__ __forceinline__ ushort_t f2bf(float f) {
    union { float f; uint_t u; } c; c.f = f;
    uint_t u = c.u;
    return (ushort_t)((u + 0x7fffu + ((u >> 16) & 1u)) >> 16);   // RNE
}
__device__ __forceinline__ float bf2f(ushort_t h) {
    union { uint_t u; float f; } c; c.u = ((uint_t)h) << 16;
    return c.f;
}
// tanh(x) = 1 - 2/(e^{2x}+1); exp2-based, saturates correctly at +/-1.
__device__ __forceinline__ float tanh_fast(float x) {
    float t = __builtin_amdgcn_exp2f(x * 2.88539008f);   // e^{2x}
    return 1.0f - 2.0f * __builtin_amdgcn_rcpf(t + 1.0f);
}

// ---------------------------------------------------------------------------
// k1: xw[t][b][n] = bf16(x[b,t,:] @ W_x + b_x + b_h). Transposed MFMA:
// A = W_x^T (m = n), B = x^T (n-operand = b).
// Grid (2, 256), 512 threads: WG tile = 4 t x 64 b x 256 n.
// Wave w: t_loc = w&3, nsub = (w>>2)*128 -> 8 mt x 4 bt acc (128 regs).
// ---------------------------------------------------------------------------
__global__ __launch_bounds__(512) void k1_xproj(
    const float* __restrict__ x, const float* __restrict__ Wx,
    const float* __restrict__ bx, const float* __restrict__ bh,
    ushort_t* __restrict__ xw)
{
    __shared__ __align__(16) ushort_t Wl[256 * 40];      // [n_local][k]
    __shared__ __align__(16) ushort_t Xl[4][64 * 40];    // [tt][b][k]

    const int n0    = blockIdx.x * 256;
    const int t0    = blockIdx.y * 4;
    const int tid   = threadIdx.x;
    const int wave  = tid >> 6;
    const int lane  = tid & 63;
    const int lm    = lane & 15;
    const int quad  = lane >> 4;
    const int t_loc = wave & 3;
    const int nsub  = (wave >> 2) * 128;

    f32x4 acc[8][4];
    #pragma unroll
    for (int mt = 0; mt < 8; ++mt)
        #pragma unroll
        for (int bt = 0; bt < 4; ++bt) acc[mt][bt] = (f32x4){0.f, 0.f, 0.f, 0.f};

    const int wk = tid >> 4, wc = (tid & 15) * 16;   // W staging: k-row, 16 n's
    const int xb = tid >> 3, xc = (tid & 7) * 4;     // X staging: b-row, 4 k's

    for (int kb = 0; kb < 16; ++kb) {
        { // stage W_x swizzled: Wl[n][k] = Wx[kb*32+wk][n0+wc+j]
            const float* wp = Wx + (size_t)(kb * 32 + wk) * HID + n0 + wc;
            #pragma unroll
            for (int j = 0; j < 16; ++j) Wl[(wc + j) * 40 + wk] = f2bf(wp[j]);
        }
        #pragma unroll
        for (int tt = 0; tt < 4; ++tt) { // stage x rows, b64 writes
            const float* ap = x + ((size_t)xb * T_STEPS + t0 + tt) * HID + kb * 32 + xc;
            float4_t v = *(const float4_t*)ap;
            short4_t pk;
            #pragma unroll
            for (int j = 0; j < 4; ++j) pk[j] = (short)f2bf(v[j]);
            *(short4_t*)&Xl[tt][xb * 40 + xc] = pk;
        }
        __syncthreads();
        short8 afr[8];
        #pragma unroll
        for (int mt = 0; mt < 8; ++mt)
            afr[mt] = *(const short8*)&Wl[(nsub + mt * 16 + lm) * 40 + quad * 8];
        #pragma unroll
        for (int bt = 0; bt < 4; ++bt) {
            short8 bfr = *(const short8*)&Xl[t_loc][(bt * 16 + lm) * 40 + quad * 8];
            #pragma unroll
            for (int mt = 0; mt < 8; ++mt)
                acc[mt][bt] = __builtin_amdgcn_mfma_f32_16x16x32_bf16(afr[mt], bfr, acc[mt][bt], 0, 0, 0);
        }
        __syncthreads();
    }

    // D layout: col = b = lm (+bt*16), row = n_local = quad*4+r (+nsub+mt*16)
    #pragma unroll
    for (int mt = 0; mt < 8; ++mt) {
        float biasv[4];
        #pragma unroll
        for (int r = 0; r < 4; ++r) {
            int n = n0 + nsub + mt * 16 + quad * 4 + r;
            biasv[r] = bx[n] + bh[n];
        }
        #pragma unroll
        for (int bt = 0; bt < 4; ++bt) {
            short4_t pk;
            #pragma unroll
            for (int r = 0; r < 4; ++r) pk[r] = (short)f2bf(acc[mt][bt][r] + biasv[r]);
            *(short4_t*)&xw[((size_t)(t0 + t_loc) * 64 + bt * 16 + lm) * HID
                            + n0 + nsub + mt * 16 + quad * 4] = pk;
        }
    }
}

// ---------------------------------------------------------------------------
// k2: grid=4 x 512 threads (8 waves, 2/SIMD). Wave owns 64 cols.
// LDS (ushort):
//   hT[2][8192] : h B-frags, frag-linear, double-buffered (2 x 16 KB)
//   Wl[65536]   : W_h A-frags for k in [384,512) (128 KB)
// hT element (b,k): (kt*64 + ((k>>3)&3)*16 + b)*8 + (k&7), kt = k>>5.
// Wl frag c = (ktp*32 + mtg)*64 + l: m = n = mtg*16+(l&15),
//   k = (12+ktp)*32 + (l>>4)*8 + j.
// ---------------------------------------------------------------------------
__global__ __launch_bounds__(512, 2) void k2_scan(
    const ushort_t* __restrict__ xw, const float* __restrict__ Wh,
    const float* __restrict__ Wfc, const float* __restrict__ bfc,
    float* __restrict__ out)
{
    __shared__ __align__(16) ushort_t hT[2][8192];
    __shared__ __align__(16) ushort_t Wl[65536];

    const int tid  = threadIdx.x;
    const int wave = tid >> 6;
    const int lane = tid & 63;
    const int lm   = lane & 15;
    const int quad = lane >> 4;
    const int rowbase = blockIdx.x * 16;   // batch rows
    const int colb    = wave * 64;         // wave's first output column

    // h_0 = 0 (buffer 0 only; buffer 1 fully written at t=0)
    for (int i = tid; i < 8192; i += 512) hT[0][i] = 0;

    // Wl init: 4*32*64 = 8192 frags
    for (int i = 0; i < 16; ++i) {
        int c   = i * 512 + tid;
        int l   = c & 63;
        int mtg = (c >> 6) & 31;
        int ktp = c >> 11;
        int n   = mtg * 16 + (l & 15);
        int kb  = (12 + ktp) * 32 + (l >> 4) * 8;
        short8 w;
        #pragma unroll
        for (int j = 0; j < 8; ++j) w[j] = (short)f2bf(Wh[(size_t)(kb + j) * HID + n]);
        *(short8*)&Wl[(size_t)c * 8] = w;
    }

    // wfA[mt][kt]: A[m = colb+mt*16+lm][k = kt*32+quad*8+j], k in [0,384).
    // ALL register indices compile-time; 192 frag-regs (slack below 256 cap).
    short8 wfA[4][12];
    #pragma unroll
    for (int mt = 0; mt < 4; ++mt) {
        const int n = colb + mt * 16 + lm;
        #pragma unroll
        for (int kt = 0; kt < 12; ++kt) {
            short8 w;
            #pragma unroll
            for (int j = 0; j < 8; ++j)
                w[j] = (short)f2bf(Wh[(size_t)(kt * 32 + quad * 8 + j) * HID + n]);
            wfA[mt][kt] = w;
        }
    }
    __syncthreads();

    // strength-reduced xw pointer (per-lane base; bump by 64*HID per step)
    const ushort_t* xp = xw + ((size_t)rowbase + lm) * HID + colb + quad * 4;

    for (int t = 0; t < T_STEPS; ++t, xp += (size_t)64 * HID) {
        // xw loads: one b64 per mt (consumed only pre-tanh -> latency hidden)
        short4_t xv[4];
        #pragma unroll
        for (int mt = 0; mt < 4; ++mt)
            xv[mt] = *(const short4_t*)(xp + mt * 16);

        f32x4 acc[4];
        #pragma unroll
        for (int mt = 0; mt < 4; ++mt) acc[mt] = (f32x4){0.f, 0.f, 0.f, 0.f};

        const ushort_t* cur = hT[t & 1];
        // k in [0,384): A from registers, B (h) from LDS
        #pragma unroll
        for (int kt = 0; kt < 12; ++kt) {
            short8 b = *(const short8*)&cur[(kt * 64 + lane) * 8];
            #pragma unroll
            for (int mt = 0; mt < 4; ++mt)
                acc[mt] = __builtin_amdgcn_mfma_f32_16x16x32_bf16(wfA[mt][kt], b, acc[mt], 0, 0, 0);
        }
        // k in [384,512): A from LDS
        #pragma unroll
        for (int ktp = 0; ktp < 4; ++ktp) {
            short8 b = *(const short8*)&cur[((12 + ktp) * 64 + lane) * 8];
            #pragma unroll
            for (int mt = 0; mt < 4; ++mt) {
                short8 a = *(const short8*)&Wl[(size_t)((ktp * 32 + wave * 4 + mt) * 64 + lane) * 8];
                acc[mt] = __builtin_amdgcn_mfma_f32_16x16x32_bf16(a, b, acc[mt], 0, 0, 0);
            }
        }

        // h_{t+1} = tanh(acc + xw) -> other hT buffer (packed b64 stores)
        ushort_t* nxt = hT[(t + 1) & 1];
        #pragma unroll
        for (int mt = 0; mt < 4; ++mt) {
            float v0 = tanh_fast(acc[mt][0] + bf2f((ushort_t)xv[mt][0]));
            float v1 = tanh_fast(acc[mt][1] + bf2f((ushort_t)xv[mt][1]));
            float v2 = tanh_fast(acc[mt][2] + bf2f((ushort_t)xv[mt][2]));
            float v3 = tanh_fast(acc[mt][3] + bf2f((ushort_t)xv[mt][3]));
            union { short4_t v; __hip_bfloat162 h[2]; } cv;
            cv.h[0] = __float22bfloat162_rn(float2{v0, v1});
            cv.h[1] = __float22bfloat162_rn(float2{v2, v3});
            const int n = colb + mt * 16 + quad * 4;
            *(short4_t*)&nxt[((n >> 5) * 64 + ((n >> 3) & 3) * 16 + lm) * 8 + (n & 7)] = cv.v;
        }

        __syncthreads();   // ONE barrier: h_{t+1} complete before next step reads
    }

    // fused FC epilogue: out[rowbase+b] = h_T[b,:] . W_fc + b_fc
    const ushort_t* fin = hT[T_STEPS & 1];
    #pragma unroll
    for (int bb = 0; bb < 2; ++bb) {
        const int b = wave * 2 + bb;
        short8 hv = *(const short8*)&fin[(((lane >> 2) * 64 + (lane & 3) * 16 + b) * 8)];
        float s = 0.f;
        #pragma unroll
        for (int j = 0; j < 8; ++j) s += bf2f((ushort_t)hv[j]) * Wfc[lane * 8 + j];
        #pragma unroll
        for (int off = 32; off; off >>= 1) s += __shfl_down(s, off, 64);
        if (lane == 0) out[rowbase + b] = s + bfc[0];
    }
}

// ---------------------------------------------------------------------------
extern "C" void kernel_launch(void* const* d_in, const int* in_sizes, int n_in,
                              void* d_out, int out_size, void* d_ws, size_t ws_size,
                              hipStream_t stream)
{
    const float* x   = (const float*)d_in[0];
    const float* Wx  = (const float*)d_in[1];
    const float* bx  = (const float*)d_in[2];
    const float* Wh  = (const float*)d_in[3];
    const float* bh  = (const float*)d_in[4];
    const float* Wfc = (const float*)d_in[5];
    const float* bfc = (const float*)d_in[6];
    float* out = (float*)d_out;

    // ws: xw bf16 [1024 t][64 b][512 n] = 64 MiB
    ushort_t* xw = (ushort_t*)d_ws;

    k1_xproj<<<dim3(2, 256), 512, 0, stream>>>(x, Wx, bx, bh, xw);
    k2_scan <<<dim3(4),      512, 0, stream>>>(xw, Wh, Wfc, bfc, out);
}